// Round 1
// baseline (38777.994 us; speedup 1.0000x reference)
//
#include <hip/hip_runtime.h>
#include <math.h>

// Problem constants
#define NB   4096   // batch
#define HID  512    // hidden
#define G4H  2048   // 4*HID
#define EDIM 256
#define FINP 8
#define TSTEPS 64
#define FWIN 32

__device__ __forceinline__ float sigf(float x) { return 1.0f / (1.0f + __expf(-x)); }

// ---------------------------------------------------------------------------
// Fold kernel: Wf0 = Wih0 @ We  (2048x8);  bf0 = Wih0@be + bih0 + bhh0;
//              bs1 = bih1 + bhh1
// ---------------------------------------------------------------------------
__global__ void fold_kernel(const float* __restrict__ Wih0, const float* __restrict__ We,
                            const float* __restrict__ be, const float* __restrict__ bih0,
                            const float* __restrict__ bhh0, const float* __restrict__ bih1,
                            const float* __restrict__ bhh1,
                            float* __restrict__ Wf0, float* __restrict__ bf0,
                            float* __restrict__ bs1)
{
    int j = blockIdx.x * blockDim.x + threadIdx.x;
    if (j >= G4H) return;
    float acc[FINP];
#pragma unroll
    for (int f = 0; f < FINP; ++f) acc[f] = 0.f;
    float bacc = 0.f;
    for (int e = 0; e < EDIM; ++e) {
        float w = Wih0[(size_t)j * EDIM + e];
        bacc += w * be[e];
#pragma unroll
        for (int f = 0; f < FINP; ++f) acc[f] += w * We[e * FINP + f];
    }
#pragma unroll
    for (int f = 0; f < FINP; ++f) Wf0[(size_t)j * FINP + f] = acc[f];
    bf0[j] = bacc + bih0[j] + bhh0[j];
    bs1[j] = bih1[j] + bhh1[j];
}

// ---------------------------------------------------------------------------
// Shared tiled-GEMM machinery: 64 rows x 64 cols tile, K in chunks of 16.
// 256 threads; thread (tx=tid&15, ty=tid>>4) computes acc[r][g] =
//   C[m0+ty*4+r][colmap(g,tx)] for r,g in 0..3.
// ---------------------------------------------------------------------------
#define FMA_BLOCK \
    acc[0][0]+=a0*b0; acc[0][1]+=a0*b1; acc[0][2]+=a0*b2; acc[0][3]+=a0*b3; \
    acc[1][0]+=a1*b0; acc[1][1]+=a1*b1; acc[1][2]+=a1*b2; acc[1][3]+=a1*b3; \
    acc[2][0]+=a2*b0; acc[2][1]+=a2*b1; acc[2][2]+=a2*b2; acc[2][3]+=a2*b3; \
    acc[3][0]+=a3*b0; acc[3][1]+=a3*b1; acc[3][2]+=a3*b2; acc[3][3]+=a3*b3;

__device__ __forceinline__ void gemm_k512(const float* __restrict__ A,
                                          const float* __restrict__ W,
                                          int m0, int jrow,
                                          int r, int k4, int tx, int ty,
                                          float (&As)[64][20], float (&Ws)[64][20],
                                          float (&acc)[4][4])
{
    const float* arow = A + (size_t)(m0 + r) * HID + k4;
    const float* wrow = W + (size_t)jrow * HID + k4;
    for (int k0 = 0; k0 < HID; k0 += 16) {
        __syncthreads();   // prior-iteration (or prior-pass) LDS reads complete
        *(float4*)&As[r][k4] = *(const float4*)(arow + k0);
        *(float4*)&Ws[r][k4] = *(const float4*)(wrow + k0);
        __syncthreads();
#pragma unroll
        for (int k = 0; k < 16; ++k) {
            float a0 = As[ty*4+0][k], a1 = As[ty*4+1][k], a2 = As[ty*4+2][k], a3 = As[ty*4+3][k];
            float b0 = Ws[tx][k], b1 = Ws[tx+16][k], b2 = Ws[tx+32][k], b3 = Ws[tx+48][k];
            FMA_BLOCK
        }
    }
}

__device__ __forceinline__ void lstm_epilogue(float (&acc)[4][4], const float* __restrict__ bias,
                                              int m0, int hu, int ty,
                                              float* __restrict__ hout, float* __restrict__ c)
{
    float bi = bias[hu], bf = bias[HID + hu], bg = bias[2*HID + hu], bo = bias[3*HID + hu];
#pragma unroll
    for (int r = 0; r < 4; ++r) {
        int n = m0 + ty*4 + r;
        size_t idx = (size_t)n * HID + hu;
        float iv = sigf(acc[r][0] + bi);
        float fv = sigf(acc[r][1] + bf);
        float gv = tanhf(acc[r][2] + bg);
        float ov = sigf(acc[r][3] + bo);
        float cn = fv * c[idx] + iv * gv;
        c[idx] = cn;
        hout[idx] = ov * tanhf(cn);
    }
}

// ---------------------------------------------------------------------------
// LSTM cell, layer-0 flavor: gates = xA(Nx8) @ Wf^T + hin @ Whh^T + bias
// grid: (4096/64, 512/16) = (64, 32)
// ---------------------------------------------------------------------------
__global__ __launch_bounds__(256)
void lstm_cell_x8(const float* __restrict__ xA, int sx,
                  const float* __restrict__ Wf,
                  const float* __restrict__ hin,
                  const float* __restrict__ Whh,
                  const float* __restrict__ bias,
                  float* __restrict__ hout, float* __restrict__ c)
{
    __shared__ float As[64][20];
    __shared__ float Ws[64][20];
    int tid = threadIdx.x;
    int tx = tid & 15, ty = tid >> 4;
    int r = tid >> 2, k4 = (tid & 3) * 4;
    int m0 = blockIdx.x * 64, hu0 = blockIdx.y * 16;
    int jrow = (r >> 4) * HID + hu0 + (r & 15);

    float acc[4][4];
#pragma unroll
    for (int i = 0; i < 4; ++i)
#pragma unroll
        for (int j = 0; j < 4; ++j) acc[i][j] = 0.f;

    // --- x-part, K=8 ---
    if (tid < 128) {
        int r2 = tid >> 1, kk = (tid & 1) * 4;
        int j2 = (r2 >> 4) * HID + hu0 + (r2 & 15);
        *(float4*)&As[r2][kk] = *(const float4*)&xA[(size_t)(m0 + r2) * sx + kk];
        *(float4*)&Ws[r2][kk] = *(const float4*)&Wf[(size_t)j2 * FINP + kk];
    }
    __syncthreads();
#pragma unroll
    for (int k = 0; k < 8; ++k) {
        float a0 = As[ty*4+0][k], a1 = As[ty*4+1][k], a2 = As[ty*4+2][k], a3 = As[ty*4+3][k];
        float b0 = Ws[tx][k], b1 = Ws[tx+16][k], b2 = Ws[tx+32][k], b3 = Ws[tx+48][k];
        FMA_BLOCK
    }
    // --- h-part, K=512 ---
    gemm_k512(hin, Whh, m0, jrow, r, k4, tx, ty, As, Ws, acc);

    lstm_epilogue(acc, bias, m0, hu0 + tx, ty, hout, c);
}

// ---------------------------------------------------------------------------
// LSTM cell, layer-1 flavor: gates = A1 @ W1^T + hin @ Whh^T + bias (both K=512)
// ---------------------------------------------------------------------------
__global__ __launch_bounds__(256)
void lstm_cell_hh(const float* __restrict__ A1, const float* __restrict__ W1,
                  const float* __restrict__ hin, const float* __restrict__ Whh,
                  const float* __restrict__ bias,
                  float* __restrict__ hout, float* __restrict__ c)
{
    __shared__ float As[64][20];
    __shared__ float Ws[64][20];
    int tid = threadIdx.x;
    int tx = tid & 15, ty = tid >> 4;
    int r = tid >> 2, k4 = (tid & 3) * 4;
    int m0 = blockIdx.x * 64, hu0 = blockIdx.y * 16;
    int jrow = (r >> 4) * HID + hu0 + (r & 15);

    float acc[4][4];
#pragma unroll
    for (int i = 0; i < 4; ++i)
#pragma unroll
        for (int j = 0; j < 4; ++j) acc[i][j] = 0.f;

    gemm_k512(A1, W1, m0, jrow, r, k4, tx, ty, As, Ws, acc);
    gemm_k512(hin, Whh, m0, jrow, r, k4, tx, ty, As, Ws, acc);

    lstm_epilogue(acc, bias, m0, hu0 + tx, ty, hout, c);
}

// ---------------------------------------------------------------------------
// fc1: Z = A @ W^T + b   (4096x512, K=512).  grid (64, 8)
// ---------------------------------------------------------------------------
__global__ __launch_bounds__(256)
void fc1_gemm(const float* __restrict__ A, const float* __restrict__ W,
              const float* __restrict__ bias, float* __restrict__ Z)
{
    __shared__ float As[64][20];
    __shared__ float Ws[64][20];
    int tid = threadIdx.x;
    int tx = tid & 15, ty = tid >> 4;
    int r = tid >> 2, k4 = (tid & 3) * 4;
    int m0 = blockIdx.x * 64, c0 = blockIdx.y * 64;
    int jrow = c0 + r;

    float acc[4][4];
#pragma unroll
    for (int i = 0; i < 4; ++i)
#pragma unroll
        for (int j = 0; j < 4; ++j) acc[i][j] = 0.f;

    gemm_k512(A, W, m0, jrow, r, k4, tx, ty, As, Ws, acc);

#pragma unroll
    for (int rr = 0; rr < 4; ++rr) {
        int n = m0 + ty*4 + rr;
#pragma unroll
        for (int g = 0; g < 4; ++g) {
            int col = c0 + g*16 + tx;
            Z[(size_t)n * HID + col] = acc[rr][g] + bias[col];
        }
    }
}

// ---------------------------------------------------------------------------
// LayerNorm + ReLU + fc2 (8 outputs), one wave per row.  grid 1024 x 256thr
// out points at d_out + s*8; row stride 256 floats.
// ---------------------------------------------------------------------------
__global__ __launch_bounds__(256)
void ln_fc2_kernel(const float* __restrict__ Z, const float* __restrict__ lng,
                   const float* __restrict__ lnb, const float* __restrict__ w2,
                   const float* __restrict__ b2, float* __restrict__ out)
{
    int wave = threadIdx.x >> 6;
    int lane = threadIdx.x & 63;
    int n = blockIdx.x * 4 + wave;
    const float* zr = Z + (size_t)n * HID;

    float v[8];
    float s1 = 0.f, s2 = 0.f;
#pragma unroll
    for (int j = 0; j < 8; ++j) {
        v[j] = zr[lane + j*64];
        s1 += v[j];
        s2 += v[j] * v[j];
    }
#pragma unroll
    for (int off = 32; off; off >>= 1) {
        s1 += __shfl_down(s1, off);
        s2 += __shfl_down(s2, off);
    }
    s1 = __shfl(s1, 0);
    s2 = __shfl(s2, 0);
    float mu = s1 * (1.f/512.f);
    float var = s2 * (1.f/512.f) - mu*mu;
    float rs = rsqrtf(var + 1e-5f);

    float y[8];
#pragma unroll
    for (int f = 0; f < 8; ++f) y[f] = 0.f;
#pragma unroll
    for (int j = 0; j < 8; ++j) {
        int h = lane + j*64;
        float zn = (v[j] - mu) * rs * lng[h] + lnb[h];
        zn = fmaxf(zn, 0.f);
#pragma unroll
        for (int f = 0; f < 8; ++f) y[f] += zn * w2[f*HID + h];
    }
#pragma unroll
    for (int f = 0; f < 8; ++f)
#pragma unroll
        for (int off = 32; off; off >>= 1) y[f] += __shfl_down(y[f], off);

    if (lane == 0) {
#pragma unroll
        for (int f = 0; f < 8; ++f) out[(size_t)n * 256 + f] = y[f] + b2[f];
    }
}

// ---------------------------------------------------------------------------
extern "C" void kernel_launch(void* const* d_in, const int* in_sizes, int n_in,
                              void* d_out, int out_size, void* d_ws, size_t ws_size,
                              hipStream_t stream)
{
    const float* x    = (const float*)d_in[0];
    const float* We   = (const float*)d_in[1];
    const float* be   = (const float*)d_in[2];
    const float* Wih0 = (const float*)d_in[3];
    const float* Whh0 = (const float*)d_in[4];
    const float* bih0 = (const float*)d_in[5];
    const float* bhh0 = (const float*)d_in[6];
    const float* Wih1 = (const float*)d_in[7];
    const float* Whh1 = (const float*)d_in[8];
    const float* bih1 = (const float*)d_in[9];
    const float* bhh1 = (const float*)d_in[10];
    const float* fc1w = (const float*)d_in[11];
    const float* fc1b = (const float*)d_in[12];
    const float* lng  = (const float*)d_in[13];
    const float* lnb  = (const float*)d_in[14];
    const float* fc2w = (const float*)d_in[15];
    const float* fc2b = (const float*)d_in[16];
    float* out = (float*)d_out;

    float* ws  = (float*)d_ws;
    float* Wf0 = ws; ws += (size_t)G4H * FINP;
    float* bf0 = ws; ws += G4H;
    float* bs1 = ws; ws += G4H;
    const size_t S = (size_t)NB * HID;
    float* h0a = ws; ws += S;
    float* h0b = ws; ws += S;
    float* c0  = ws; ws += S;
    float* h1a = ws; ws += S;
    float* h1b = ws; ws += S;
    float* c1  = ws; ws += S;
    float* zb  = ws; ws += S;

    hipMemsetAsync(h0a, 0, S * sizeof(float), stream);
    hipMemsetAsync(c0,  0, S * sizeof(float), stream);
    hipMemsetAsync(h1a, 0, S * sizeof(float), stream);
    hipMemsetAsync(c1,  0, S * sizeof(float), stream);

    fold_kernel<<<8, 256, 0, stream>>>(Wih0, We, be, bih0, bhh0, bih1, bhh1, Wf0, bf0, bs1);

    dim3 cg(NB/64, HID/16);   // (64, 32)
    dim3 cb(256);

    // ----- encoder: 63 steps -----
    for (int t = 0; t < TSTEPS - 1; ++t) {
        lstm_cell_x8<<<cg, cb, 0, stream>>>(x + (size_t)t * FINP, TSTEPS * FINP,
                                            Wf0, h0a, Whh0, bf0, h0b, c0);
        lstm_cell_hh<<<cg, cb, 0, stream>>>(h0b, Wih1, h1a, Whh1, bs1, h1b, c1);
        float* tmp;
        tmp = h0a; h0a = h0b; h0b = tmp;
        tmp = h1a; h1a = h1b; h1b = tmp;
    }

    // ----- decoder: 32 steps -----
    for (int s = 0; s < FWIN; ++s) {
        const float* xA = (s == 0) ? (x + (size_t)(TSTEPS - 1) * FINP)
                                   : (out + (size_t)(s - 1) * FINP);
        int sx = (s == 0) ? (TSTEPS * FINP) : (FWIN * FINP);
        lstm_cell_x8<<<cg, cb, 0, stream>>>(xA, sx, Wf0, h0a, Whh0, bf0, h0b, c0);
        lstm_cell_hh<<<cg, cb, 0, stream>>>(h0b, Wih1, h1a, Whh1, bs1, h1b, c1);
        fc1_gemm<<<dim3(NB/64, HID/64), cb, 0, stream>>>(h1b, fc1w, fc1b, zb);
        ln_fc2_kernel<<<NB/4, 256, 0, stream>>>(zb, lng, lnb, fc2w, fc2b, out + (size_t)s * FINP);
        float* tmp;
        tmp = h0a; h0a = h0b; h0b = tmp;
        tmp = h1a; h1a = h1b; h1b = tmp;
    }
}

// Round 2
// 5442.334 us; speedup vs baseline: 7.1253x; 7.1253x over previous
//
#include <hip/hip_runtime.h>
#include <math.h>

// Problem constants
#define NB   4096
#define HID  512
#define G4H  2048
#define EDIM 256
#define FINP 8
#define TSTEPS 64
#define FWIN 32

typedef __bf16 bf16;
typedef bf16  bf16x8 __attribute__((ext_vector_type(8)));
typedef float f32x4  __attribute__((ext_vector_type(4)));

__device__ __forceinline__ float sigf(float x) { return 1.0f / (1.0f + __expf(-x)); }
__device__ __forceinline__ float tanhf_(float x) { return 2.0f * sigf(2.0f * x) - 1.0f; }

__device__ __forceinline__ void gload16(const void* g, void* l) {
    __builtin_amdgcn_global_load_lds((const __attribute__((address_space(1))) void*)g,
                                     (__attribute__((address_space(3))) void*)l, 16, 0, 0);
}

// ---------------------------------------------------------------------------
// Core 128x128-tile bf16 MFMA pass over K=512 (m97 structure: BK=32, 2-barrier,
// global_load_lds width 16). 256 threads = 4 waves (2x2 of 64x64).
// W is row-major [N][K] (B^T form). acc[m][n] = 16x16 frag (m=rows,n=cols).
// ---------------------------------------------------------------------------
__device__ __forceinline__ void gemm_pass(
    const bf16* __restrict__ A, int lda,
    const bf16* __restrict__ W, int ldw,
    int m0, int n0,
    bf16* As, bf16* Ws,
    f32x4 (&acc)[4][4])
{
    const int tid  = threadIdx.x;
    const int lane = tid & 63;
    const int w    = tid >> 6;
    const int wr   = w >> 1, wc = w & 1;
    const int koct = lane >> 4;
    const int l16  = lane & 15;

    const int lin0 = tid;
    const int lin1 = tid + 256;
    const int ar0 = lin0 >> 2, ac0 = (lin0 & 3) * 8;
    const int ar1 = lin1 >> 2, ac1 = (lin1 & 3) * 8;

    for (int k0 = 0; k0 < HID; k0 += 32) {
        __syncthreads();   // prior-iteration LDS reads complete
        gload16(A + (size_t)(m0 + ar0) * lda + k0 + ac0, As + lin0 * 8);
        gload16(A + (size_t)(m0 + ar1) * lda + k0 + ac1, As + lin1 * 8);
        gload16(W + (size_t)(n0 + ar0) * ldw + k0 + ac0, Ws + lin0 * 8);
        gload16(W + (size_t)(n0 + ar1) * ldw + k0 + ac1, Ws + lin1 * 8);
        __syncthreads();   // compiler drains vmcnt(0) before s_barrier
        bf16x8 af[4], bfr[4];
#pragma unroll
        for (int m = 0; m < 4; ++m)
            af[m] = *(const bf16x8*)&As[(wr * 64 + m * 16 + l16) * 32 + koct * 8];
#pragma unroll
        for (int n = 0; n < 4; ++n)
            bfr[n] = *(const bf16x8*)&Ws[(wc * 64 + n * 16 + l16) * 32 + koct * 8];
#pragma unroll
        for (int m = 0; m < 4; ++m)
#pragma unroll
            for (int n = 0; n < 4; ++n)
                acc[m][n] = __builtin_amdgcn_mfma_f32_16x16x32_bf16(af[m], bfr[n], acc[m][n], 0, 0, 0);
    }
}

// ---------------------------------------------------------------------------
// LSTM cell kernel. Weight rows pre-reordered: j_new = (hu>>4)*64 + gate*16
// + (hu&15)  ->  wave's 4 N-frags are gates i,f,g,o of 16 hus (lane-local).
// NPASS=1 (+x-dot): layer 0.  NPASS=2: layer 1.
// grid (32,16), 256 threads.
// ---------------------------------------------------------------------------
template<int NPASS, bool HASX>
__global__ __launch_bounds__(256)
void lstm_mfma(const bf16* __restrict__ A1, const bf16* __restrict__ W1,
               const bf16* __restrict__ A2, const bf16* __restrict__ W2,
               const float* __restrict__ Wfc, const float* __restrict__ bias,
               const float* __restrict__ xA, int sx,
               float* __restrict__ cst, bf16* __restrict__ hdst)
{
    __shared__ bf16 As[128 * 32];
    __shared__ bf16 Ws[128 * 32];
    f32x4 acc[4][4];
#pragma unroll
    for (int m = 0; m < 4; ++m)
#pragma unroll
        for (int n = 0; n < 4; ++n)
            acc[m][n] = (f32x4){0.f, 0.f, 0.f, 0.f};

    const int m0 = blockIdx.x * 128, n0 = blockIdx.y * 128;
    gemm_pass(A1, 1024, W1, 512, m0, n0, As, Ws, acc);
    if constexpr (NPASS == 2)
        gemm_pass(A2, 1024, W2, 512, m0, n0, As, Ws, acc);

    const int tid = threadIdx.x, lane = tid & 63, w = tid >> 6;
    const int wr = w >> 1, wc = w & 1, l16 = lane & 15, lq = lane >> 4;
    const int hu = blockIdx.y * 32 + wc * 16 + l16;
    const int jb = n0 + wc * 64 + l16;

    float bq[4];
    float wf[4][8];
#pragma unroll
    for (int g = 0; g < 4; ++g) {
        bq[g] = bias[jb + g * 16];
        if constexpr (HASX) {
            const float* wrow = Wfc + (size_t)(jb + g * 16) * 8;
            f32x4 w0 = *(const f32x4*)wrow;
            f32x4 w1 = *(const f32x4*)(wrow + 4);
#pragma unroll
            for (int e = 0; e < 4; ++e) { wf[g][e] = w0[e]; wf[g][e + 4] = w1[e]; }
        }
    }

#pragma unroll
    for (int m = 0; m < 4; ++m) {
        const int rb = m0 + wr * 64 + m * 16 + lq * 4;
#pragma unroll
        for (int q = 0; q < 4; ++q) {
            const int r = rb + q;
            float d0 = 0.f, d1 = 0.f, d2 = 0.f, d3 = 0.f;
            if constexpr (HASX) {
                const float* xr = xA + (size_t)r * sx;
#pragma unroll
                for (int e = 0; e < 8; ++e) {
                    float xv = xr[e];
                    d0 += xv * wf[0][e]; d1 += xv * wf[1][e];
                    d2 += xv * wf[2][e]; d3 += xv * wf[3][e];
                }
            }
            float gi = acc[m][0][q] + bq[0] + d0;
            float gf = acc[m][1][q] + bq[1] + d1;
            float gg = acc[m][2][q] + bq[2] + d2;
            float go = acc[m][3][q] + bq[3] + d3;
            float iv = sigf(gi), fv = sigf(gf), gv = tanhf_(gg), ov = sigf(go);
            size_t ci = (size_t)r * HID + hu;
            float cn = fv * cst[ci] + iv * gv;
            cst[ci] = cn;
            hdst[(size_t)r * 1024 + hu] = (bf16)(ov * tanhf_(cn));
        }
    }
}

// ---------------------------------------------------------------------------
// fc1: Z = h1 @ fc1w^T + b (fp32 out). grid (32,4), plain column order.
// ---------------------------------------------------------------------------
__global__ __launch_bounds__(256)
void fc1_mfma(const bf16* __restrict__ A, const bf16* __restrict__ W,
              const float* __restrict__ bias, float* __restrict__ Z)
{
    __shared__ bf16 As[128 * 32];
    __shared__ bf16 Ws[128 * 32];
    f32x4 acc[4][4];
#pragma unroll
    for (int m = 0; m < 4; ++m)
#pragma unroll
        for (int n = 0; n < 4; ++n)
            acc[m][n] = (f32x4){0.f, 0.f, 0.f, 0.f};

    const int m0 = blockIdx.x * 128, n0 = blockIdx.y * 128;
    gemm_pass(A, 1024, W, 512, m0, n0, As, Ws, acc);

    const int tid = threadIdx.x, lane = tid & 63, w = tid >> 6;
    const int wr = w >> 1, wc = w & 1, l16 = lane & 15, lq = lane >> 4;
#pragma unroll
    for (int m = 0; m < 4; ++m) {
        const int rb = m0 + wr * 64 + m * 16 + lq * 4;
#pragma unroll
        for (int n = 0; n < 4; ++n) {
            const int col = n0 + wc * 64 + n * 16 + l16;
            float bv = bias[col];
#pragma unroll
            for (int q = 0; q < 4; ++q)
                Z[(size_t)(rb + q) * HID + col] = acc[m][n][q] + bv;
        }
    }
}

// ---------------------------------------------------------------------------
// LayerNorm + ReLU + fc2 (8 outs), one wave per row.
// ---------------------------------------------------------------------------
__global__ __launch_bounds__(256)
void ln_fc2_kernel(const float* __restrict__ Z, const float* __restrict__ lng,
                   const float* __restrict__ lnb, const float* __restrict__ w2,
                   const float* __restrict__ b2, float* __restrict__ out)
{
    int wave = threadIdx.x >> 6;
    int lane = threadIdx.x & 63;
    int n = blockIdx.x * 4 + wave;
    const float* zr = Z + (size_t)n * HID;

    float v[8];
    float s1 = 0.f, s2 = 0.f;
#pragma unroll
    for (int j = 0; j < 8; ++j) {
        v[j] = zr[lane + j * 64];
        s1 += v[j];
        s2 += v[j] * v[j];
    }
#pragma unroll
    for (int off = 32; off; off >>= 1) {
        s1 += __shfl_down(s1, off);
        s2 += __shfl_down(s2, off);
    }
    s1 = __shfl(s1, 0);
    s2 = __shfl(s2, 0);
    float mu = s1 * (1.f / 512.f);
    float var = s2 * (1.f / 512.f) - mu * mu;
    float rs = rsqrtf(var + 1e-5f);

    float y[8];
#pragma unroll
    for (int f = 0; f < 8; ++f) y[f] = 0.f;
#pragma unroll
    for (int j = 0; j < 8; ++j) {
        int h = lane + j * 64;
        float zn = (v[j] - mu) * rs * lng[h] + lnb[h];
        zn = fmaxf(zn, 0.f);
#pragma unroll
        for (int f = 0; f < 8; ++f) y[f] += zn * w2[f * HID + h];
    }
#pragma unroll
    for (int f = 0; f < 8; ++f)
#pragma unroll
        for (int off = 32; off; off >>= 1) y[f] += __shfl_down(y[f], off);

    if (lane == 0) {
#pragma unroll
        for (int f = 0; f < 8; ++f) out[(size_t)n * 256 + f] = y[f] + b2[f];
    }
}

// ---------------------------------------------------------------------------
// Weight preprocessing
// ---------------------------------------------------------------------------
__device__ __forceinline__ int remap_j(int j) {
    int gate = j >> 9, hu = j & 511;
    return ((hu >> 4) << 6) + (gate << 4) + (hu & 15);
}

// Wf0c = reorder(Wih0 @ We) fp32 [2048][8]; bf0c = reorder(Wih0@be + bih0 + bhh0);
// bs1c = reorder(bih1 + bhh1)
__global__ void fold_small(const float* __restrict__ Wih0, const float* __restrict__ We,
                           const float* __restrict__ be, const float* __restrict__ bih0,
                           const float* __restrict__ bhh0, const float* __restrict__ bih1,
                           const float* __restrict__ bhh1,
                           float* __restrict__ Wf0c, float* __restrict__ bf0c,
                           float* __restrict__ bs1c)
{
    int j = blockIdx.x * 256 + threadIdx.x;
    if (j >= G4H) return;
    int jn = remap_j(j);
    float acc[FINP];
#pragma unroll
    for (int f = 0; f < FINP; ++f) acc[f] = 0.f;
    float bacc = 0.f;
    for (int e = 0; e < EDIM; ++e) {
        float wv = Wih0[(size_t)j * EDIM + e];
        bacc += wv * be[e];
#pragma unroll
        for (int f = 0; f < FINP; ++f) acc[f] += wv * We[e * FINP + f];
    }
#pragma unroll
    for (int f = 0; f < FINP; ++f) Wf0c[(size_t)jn * FINP + f] = acc[f];
    bf0c[jn] = bacc + bih0[j] + bhh0[j];
    bs1c[jn] = bih1[j] + bhh1[j];
}

// Convert + row-reorder the three 2048x512 gate matrices to bf16.
__global__ void conv_w(const float* __restrict__ W0, const float* __restrict__ W1,
                       const float* __restrict__ W2,
                       bf16* __restrict__ O0, bf16* __restrict__ O1, bf16* __restrict__ O2)
{
    int j = blockIdx.x;
    int which = blockIdx.y;
    const float* src = which == 0 ? W0 : which == 1 ? W1 : W2;
    bf16* dst = which == 0 ? O0 : which == 1 ? O1 : O2;
    int jn = remap_j(j);
    for (int k = threadIdx.x; k < HID; k += 256)
        dst[(size_t)jn * HID + k] = (bf16)src[(size_t)j * HID + k];
}

__global__ void conv_fc1(const float* __restrict__ W, bf16* __restrict__ O)
{
    int j = blockIdx.x;
    for (int k = threadIdx.x; k < HID; k += 256)
        O[(size_t)j * HID + k] = (bf16)W[(size_t)j * HID + k];
}

// ---------------------------------------------------------------------------
extern "C" void kernel_launch(void* const* d_in, const int* in_sizes, int n_in,
                              void* d_out, int out_size, void* d_ws, size_t ws_size,
                              hipStream_t stream)
{
    const float* x    = (const float*)d_in[0];
    const float* We   = (const float*)d_in[1];
    const float* be   = (const float*)d_in[2];
    const float* Wih0 = (const float*)d_in[3];
    const float* Whh0 = (const float*)d_in[4];
    const float* bih0 = (const float*)d_in[5];
    const float* bhh0 = (const float*)d_in[6];
    const float* Wih1 = (const float*)d_in[7];
    const float* Whh1 = (const float*)d_in[8];
    const float* bih1 = (const float*)d_in[9];
    const float* bhh1 = (const float*)d_in[10];
    const float* fc1w = (const float*)d_in[11];
    const float* fc1b = (const float*)d_in[12];
    const float* lng  = (const float*)d_in[13];
    const float* lnb  = (const float*)d_in[14];
    const float* fc2w = (const float*)d_in[15];
    const float* fc2b = (const float*)d_in[16];
    float* out = (float*)d_out;

    char* p = (char*)d_ws;
    auto alloc = [&](size_t bytes) -> void* {
        void* r = (void*)p;
        p += (bytes + 255) & ~(size_t)255;
        return r;
    };
    bf16*  Whh0c = (bf16*)alloc((size_t)G4H * HID * 2);
    bf16*  Wih1c = (bf16*)alloc((size_t)G4H * HID * 2);
    bf16*  Whh1c = (bf16*)alloc((size_t)G4H * HID * 2);
    bf16*  fc1wb = (bf16*)alloc((size_t)HID * HID * 2);
    float* Wf0c  = (float*)alloc((size_t)G4H * FINP * 4);
    float* bf0c  = (float*)alloc((size_t)G4H * 4);
    float* bs1c  = (float*)alloc((size_t)G4H * 4);
    const size_t SLAB = (size_t)NB * 1024;
    bf16*  AB1   = (bf16*)alloc(2 * SLAB * 2);
    float* c0    = (float*)alloc((size_t)NB * HID * 4);
    float* c1    = (float*)alloc((size_t)NB * HID * 4);
    float* Z     = (float*)alloc((size_t)NB * HID * 4);

    hipMemsetAsync(AB1, 0, SLAB * 2, stream);            // slot 0: h0=h1=0
    hipMemsetAsync(c0, 0, (size_t)NB * HID * 4, stream);
    hipMemsetAsync(c1, 0, (size_t)NB * HID * 4, stream);

    fold_small<<<8, 256, 0, stream>>>(Wih0, We, be, bih0, bhh0, bih1, bhh1, Wf0c, bf0c, bs1c);
    conv_w<<<dim3(G4H, 3), 256, 0, stream>>>(Whh0, Wih1, Whh1, Whh0c, Wih1c, Whh1c);
    conv_fc1<<<HID, 256, 0, stream>>>(fc1w, fc1wb);

    dim3 lg(32, 16), lb(256);
    int pp = 0;

    // ----- encoder: 63 steps -----
    for (int t = 0; t < TSTEPS - 1; ++t) {
        bf16* Pp = AB1 + (size_t)pp * SLAB;
        bf16* Pq = AB1 + (size_t)(pp ^ 1) * SLAB;
        lstm_mfma<1, true><<<lg, lb, 0, stream>>>(Pp, Whh0c, nullptr, nullptr,
                                                  Wf0c, bf0c, x + (size_t)t * FINP, TSTEPS * FINP,
                                                  c0, Pq);
        lstm_mfma<2, false><<<lg, lb, 0, stream>>>(Pq, Wih1c, Pp + 512, Whh1c,
                                                   nullptr, bs1c, nullptr, 0,
                                                   c1, Pq + 512);
        pp ^= 1;
    }

    // ----- decoder: 32 steps -----
    for (int s = 0; s < FWIN; ++s) {
        bf16* Pp = AB1 + (size_t)pp * SLAB;
        bf16* Pq = AB1 + (size_t)(pp ^ 1) * SLAB;
        const float* xA = (s == 0) ? (x + (size_t)(TSTEPS - 1) * FINP)
                                   : (out + (size_t)(s - 1) * FINP);
        int sx = (s == 0) ? (TSTEPS * FINP) : (FWIN * FINP);
        lstm_mfma<1, true><<<lg, lb, 0, stream>>>(Pp, Whh0c, nullptr, nullptr,
                                                  Wf0c, bf0c, xA, sx, c0, Pq);
        lstm_mfma<2, false><<<lg, lb, 0, stream>>>(Pq, Wih1c, Pp + 512, Whh1c,
                                                   nullptr, bs1c, nullptr, 0,
                                                   c1, Pq + 512);
        fc1_mfma<<<dim3(32, 4), lb, 0, stream>>>(Pq + 512, fc1wb, fc1b, Z);
        ln_fc2_kernel<<<NB / 4, 256, 0, stream>>>(Z, lng, lnb, fc2w, fc2b, out + (size_t)s * FINP);
        pp ^= 1;
    }
}